// Round 4
// baseline (329.228 us; speedup 1.0000x reference)
//
#include <hip/hip_runtime.h>

#define N_NODES 100000
#define N_EDGES 3200000
#define IN_F    256
#define OUT_F   256
#define CLAMP_V 10.0f

typedef __attribute__((ext_vector_type(8))) short bf16x8;
typedef __attribute__((ext_vector_type(4))) float f32x4;

__device__ __forceinline__ float clampf(float v) {
    return fminf(fmaxf(v, -CLAMP_V), CLAMP_V);
}
// RNE float -> bf16 (inputs clamped/finite)
__device__ __forceinline__ unsigned f2bf(float f) {
    unsigned u = __float_as_uint(f);
    u += 0x7fffu + ((u >> 16) & 1u);
    return u >> 16;
}
__device__ __forceinline__ float bflo(unsigned w) { return __uint_as_float(w << 16); }
__device__ __forceinline__ float bfhi(unsigned w) { return __uint_as_float(w & 0xffff0000u); }

// ---------------------------------------------------------------------------
// Kernel 0: W fp32 [K=256][N=256] -> bf16 pre-swizzled:
// element (k,n) at ushort index  n*256 + ((k>>3) ^ (n&7))*8 + (k&7).
// ---------------------------------------------------------------------------
__global__ __launch_bounds__(256) void convert_w(
    const float* __restrict__ w, unsigned short* __restrict__ wt) {
    int i = blockIdx.x * 256 + threadIdx.x;   // 65536
    int k = i & 255, n = i >> 8;
    float v = w[(size_t)k * OUT_F + n];
    int dst = n * 256 + (((k >> 3) ^ (n & 7)) << 3) + (k & 7);
    wt[dst] = (unsigned short)f2bf(v);
}

// ---------------------------------------------------------------------------
// Kernel 1: CSR row_ptr from sorted adj_rows (binary search per row).
// ---------------------------------------------------------------------------
__global__ __launch_bounds__(256) void build_row_ptr(
    const int* __restrict__ rows, int* __restrict__ row_ptr) {
    int r = blockIdx.x * blockDim.x + threadIdx.x;
    if (r > N_NODES) return;
    int lo = 0, hi = N_EDGES;
    while (lo < hi) {
        int mid = (lo + hi) >> 1;
        if (rows[mid] < r) lo = mid + 1; else hi = mid;
    }
    row_ptr[r] = lo;
}

// ---------------------------------------------------------------------------
// Kernel 2: support(bf16) = clip(clip(x) @ W) via mfma_f32_16x16x32_bf16.
// 512 threads / 8 waves; block = 128 rows x 256 cols (full N).
// W fully in LDS (128 KB, pre-swizzled). A-fragments loaded DIRECTLY from
// global x into registers (clamp+cvt in-reg) -> zero barriers in the K-loop.
// Wave (wr,wc) in 2x4 grid owns 64 rows x 64 cols (4x4 fragments).
// Epilogue: reuse the W LDS buffer to transpose acc into coalesced stores.
// ---------------------------------------------------------------------------
__global__ __launch_bounds__(512) void gemm_mfma(
    const float* __restrict__ x, const unsigned short* __restrict__ wt,
    unsigned short* __restrict__ support) {
    __shared__ uint4 wlds[8192];    // 128 KB

    const int t    = threadIdx.x;
    const int lane = t & 63;
    const int w    = t >> 6;        // 0..7
    const int wr   = w >> 2;        // 0..1
    const int wc   = w & 3;         // 0..3
    const int l15  = lane & 15;
    const int l4   = lane >> 4;     // 0..3
    const int blockRow = blockIdx.x * 128;

    // ---- W -> LDS (linear copy; swizzle pre-applied) ----
    {
        const uint4* g = (const uint4*)wt;
        #pragma unroll
        for (int i = 0; i < 16; ++i)
            wlds[i * 512 + t] = g[i * 512 + t];
    }

    // A row pointers for this wave's 4 m-fragments (clamped for tail block)
    const float* aptr[4];
    #pragma unroll
    for (int m = 0; m < 4; ++m) {
        int r = blockRow + wr * 64 + m * 16 + l15;
        aptr[m] = x + (size_t)(r < N_NODES ? r : N_NODES - 1) * IN_F + l4 * 8;
    }

    f32x4 acc[4][4];
    #pragma unroll
    for (int m = 0; m < 4; ++m)
        #pragma unroll
        for (int n = 0; n < 4; ++n)
            acc[m][n] = (f32x4)0.f;

    __syncthreads();    // W ready

    #pragma unroll
    for (int s = 0; s < 8; ++s) {
        bf16x8 a[4], b[4];
        #pragma unroll
        for (int m = 0; m < 4; ++m) {
            float4 u0 = *(const float4*)(aptr[m] + s * 32);
            float4 u1 = *(const float4*)(aptr[m] + s * 32 + 4);
            union { unsigned u[4]; bf16x8 v; } pk;
            pk.u[0] = f2bf(clampf(u0.x)) | (f2bf(clampf(u0.y)) << 16);
            pk.u[1] = f2bf(clampf(u0.z)) | (f2bf(clampf(u0.w)) << 16);
            pk.u[2] = f2bf(clampf(u1.x)) | (f2bf(clampf(u1.y)) << 16);
            pk.u[3] = f2bf(clampf(u1.z)) | (f2bf(clampf(u1.w)) << 16);
            a[m] = pk.v;
        }
        #pragma unroll
        for (int n = 0; n < 4; ++n) {
            int ncol  = wc * 64 + n * 16 + l15;
            int chunk = ncol * 32 + ((s * 4 + l4) ^ (ncol & 7));
            b[n] = *(const bf16x8*)&wlds[chunk];
        }
        #pragma unroll
        for (int m = 0; m < 4; ++m)
            #pragma unroll
            for (int n = 0; n < 4; ++n)
                acc[m][n] = __builtin_amdgcn_mfma_f32_16x16x32_bf16(
                    a[m], b[n], acc[m][n], 0, 0, 0);
    }

    // ---- epilogue: acc -> LDS (bf16, chunk-swizzled) -> coalesced stores ----
    __syncthreads();    // all waves done reading W; safe to reuse wlds
    {
        char* sl = (char*)wlds;     // 128 rows x 512 B (64 KB)
        #pragma unroll
        for (int m = 0; m < 4; ++m) {
            #pragma unroll
            for (int n = 0; n < 4; ++n) {
                int col2 = (wc * 64 + n * 16 + l15) * 2;
                #pragma unroll
                for (int r = 0; r < 4; ++r) {
                    int row = wr * 64 + m * 16 + l4 * 4 + r;
                    int off = row * 512 + (col2 ^ (((row >> 2) & 3) << 4));
                    *(unsigned short*)(sl + off) = (unsigned short)f2bf(clampf(acc[m][n][r]));
                }
            }
        }
    }
    __syncthreads();
    {
        const uint4* sl4 = (const uint4*)wlds;
        #pragma unroll
        for (int i = 0; i < 8; ++i) {
            int c    = i * 512 + t;         // 0..4095 logical 16B chunks
            int row  = c >> 5;              // 0..127
            int q    = c & 31;              // chunk within row
            int grow = blockRow + row;
            if (grow < N_NODES) {
                uint4 v = sl4[row * 32 + (q ^ ((row >> 2) & 3))];
                *(uint4*)(support + (size_t)grow * OUT_F + q * 8) = v;
            }
        }
    }
}

// ---------------------------------------------------------------------------
// Kernel 3: out[r] = clip(relu(clip(sum val*support[c]) + bias)).
// One wave per row; lanes 0-31 even edge, 32-63 odd edge; 16B bf16x8 per
// lane. 8 edges per main iter => 4 gathers in flight (MLP 2x vs R2).
// ---------------------------------------------------------------------------
#define FMA8(g, v)                                                   \
    acc[0] += (v) * bflo((g).x); acc[1] += (v) * bfhi((g).x);        \
    acc[2] += (v) * bflo((g).y); acc[3] += (v) * bfhi((g).y);        \
    acc[4] += (v) * bflo((g).z); acc[5] += (v) * bfhi((g).z);        \
    acc[6] += (v) * bflo((g).w); acc[7] += (v) * bfhi((g).w);

__global__ __launch_bounds__(256) void spmm_out(
    const unsigned short* __restrict__ support, const int* __restrict__ row_ptr,
    const int* __restrict__ cols, const float* __restrict__ vals,
    const float* __restrict__ bias, float* __restrict__ out) {
    const int wid  = threadIdx.x >> 6;
    const int lane = threadIdx.x & 63;
    const int row  = blockIdx.x * 4 + wid;
    if (row >= N_NODES) return;

    const int e0   = row_ptr[row];
    const int e1   = row_ptr[row + 1];
    const int half = lane >> 5;
    const int c32  = lane & 31;

    const uint4* sup4 = (const uint4*)support;
    float acc[8] = {0.f,0.f,0.f,0.f,0.f,0.f,0.f,0.f};

    int e = e0;
    for (; e + 8 <= e1; e += 8) {
        int   ea = e + half,  eb = ea + 2, ec = ea + 4, ed = ea + 6;
        int   ca = __builtin_nontemporal_load(cols + ea);
        int   cb = __builtin_nontemporal_load(cols + eb);
        int   cc = __builtin_nontemporal_load(cols + ec);
        int   cd = __builtin_nontemporal_load(cols + ed);
        float va = __builtin_nontemporal_load(vals + ea);
        float vb = __builtin_nontemporal_load(vals + eb);
        float vc = __builtin_nontemporal_load(vals + ec);
        float vd = __builtin_nontemporal_load(vals + ed);
        uint4 ga = sup4[(size_t)ca * 32 + c32];
        uint4 gb = sup4[(size_t)cb * 32 + c32];
        uint4 gc = sup4[(size_t)cc * 32 + c32];
        uint4 gd = sup4[(size_t)cd * 32 + c32];
        FMA8(ga, va); FMA8(gb, vb); FMA8(gc, vc); FMA8(gd, vd);
    }
    for (; e + 4 <= e1; e += 4) {
        int   ea = e + half,  eb = ea + 2;
        int   ca = __builtin_nontemporal_load(cols + ea);
        int   cb = __builtin_nontemporal_load(cols + eb);
        float va = __builtin_nontemporal_load(vals + ea);
        float vb = __builtin_nontemporal_load(vals + eb);
        uint4 ga = sup4[(size_t)ca * 32 + c32];
        uint4 gb = sup4[(size_t)cb * 32 + c32];
        FMA8(ga, va); FMA8(gb, vb);
    }
    for (; e < e1; e += 2) {
        int   ea = e + half;
        bool  ok = ea < e1;
        int   ca = cols[ok ? ea : e];
        float va = ok ? vals[ea] : 0.f;
        uint4 ga = sup4[(size_t)ca * 32 + c32];
        FMA8(ga, va);
    }

    #pragma unroll
    for (int j = 0; j < 8; ++j)
        acc[j] += __shfl_xor(acc[j], 32);

    const float4 b4 = ((const float4*)bias)[c32 * 2 + half];
    f32x4 o;
    o.x = fminf(fmaxf(clampf(acc[half * 4 + 0]) + b4.x, 0.f), CLAMP_V);
    o.y = fminf(fmaxf(clampf(acc[half * 4 + 1]) + b4.y, 0.f), CLAMP_V);
    o.z = fminf(fmaxf(clampf(acc[half * 4 + 2]) + b4.z, 0.f), CLAMP_V);
    o.w = fminf(fmaxf(clampf(acc[half * 4 + 3]) + b4.w, 0.f), CLAMP_V);
    __builtin_nontemporal_store(o, (f32x4*)(out + (size_t)row * OUT_F + c32 * 8 + half * 4));
}

// ---------------------------------------------------------------------------
extern "C" void kernel_launch(void* const* d_in, const int* in_sizes, int n_in,
                              void* d_out, int out_size, void* d_ws, size_t ws_size,
                              hipStream_t stream) {
    const float* x        = (const float*)d_in[0];
    const int*   adj_rows = (const int*)d_in[1];
    const int*   adj_cols = (const int*)d_in[2];
    const float* adj_vals = (const float*)d_in[3];
    const float* weight   = (const float*)d_in[4];
    const float* bias     = (const float*)d_in[5];
    float*       out      = (float*)d_out;

    // workspace: support bf16 [100000][256] | row_ptr [N+1] | wt (bf16 swizzled)
    char* ws = (char*)d_ws;
    unsigned short* support = (unsigned short*)ws;                   // 51,200,000 B
    int*            row_ptr = (int*)(ws + 51200000);                 //    400,004 B
    unsigned short* wt      = (unsigned short*)(ws + 51600064);      //    131,072 B

    convert_w<<<256, 256, 0, stream>>>(weight, wt);
    build_row_ptr<<<(N_NODES + 1 + 255) / 256, 256, 0, stream>>>(adj_rows, row_ptr);
    gemm_mfma<<<(N_NODES + 127) / 128, 512, 0, stream>>>(x, wt, support);
    spmm_out<<<(N_NODES + 3) / 4, 256, 0, stream>>>(support, row_ptr, adj_cols,
                                                    adj_vals, bias, out);
}

// Round 5
// 322.761 us; speedup vs baseline: 1.0200x; 1.0200x over previous
//
#include <hip/hip_runtime.h>

#define N_NODES 100000
#define N_EDGES 3200000
#define IN_F    256
#define OUT_F   256
#define CLAMP_V 10.0f

typedef __attribute__((ext_vector_type(8))) short bf16x8;
typedef __attribute__((ext_vector_type(4))) float f32x4;

__device__ __forceinline__ float clampf(float v) {
    return fminf(fmaxf(v, -CLAMP_V), CLAMP_V);
}
// RNE float -> bf16 (inputs clamped/finite)
__device__ __forceinline__ unsigned f2bf(float f) {
    unsigned u = __float_as_uint(f);
    u += 0x7fffu + ((u >> 16) & 1u);
    return u >> 16;
}
// packed 2x f32 -> 2x bf16 in one u32 (S0 -> low 16, S1 -> high 16)
__device__ __forceinline__ unsigned cvt_pk_bf16(float lo, float hi) {
    unsigned r;
    asm("v_cvt_pk_bf16_f32 %0, %1, %2" : "=v"(r) : "v"(lo), "v"(hi));
    return r;
}
__device__ __forceinline__ float bflo(unsigned w) { return __uint_as_float(w << 16); }
__device__ __forceinline__ float bfhi(unsigned w) { return __uint_as_float(w & 0xffff0000u); }

// ---------------------------------------------------------------------------
// Kernel 0: W fp32 [K=256][N=256] -> bf16 pre-swizzled:
// element (k,n) at ushort index  n*256 + ((k>>3) ^ (n&7))*8 + (k&7).
// ---------------------------------------------------------------------------
__global__ __launch_bounds__(256) void convert_w(
    const float* __restrict__ w, unsigned short* __restrict__ wt) {
    int i = blockIdx.x * 256 + threadIdx.x;   // 65536
    int k = i & 255, n = i >> 8;
    float v = w[(size_t)k * OUT_F + n];
    int dst = n * 256 + (((k >> 3) ^ (n & 7)) << 3) + (k & 7);
    wt[dst] = (unsigned short)f2bf(v);
}

// ---------------------------------------------------------------------------
// Kernel 1: CSR row_ptr from sorted adj_rows (binary search per row).
// ---------------------------------------------------------------------------
__global__ __launch_bounds__(256) void build_row_ptr(
    const int* __restrict__ rows, int* __restrict__ row_ptr) {
    int r = blockIdx.x * blockDim.x + threadIdx.x;
    if (r > N_NODES) return;
    int lo = 0, hi = N_EDGES;
    while (lo < hi) {
        int mid = (lo + hi) >> 1;
        if (rows[mid] < r) lo = mid + 1; else hi = mid;
    }
    row_ptr[r] = lo;
}

// ---------------------------------------------------------------------------
// Kernel 2: support(bf16) = clip(clip(x) @ W) via mfma_f32_16x16x32_bf16.
// 512 threads / 8 waves; block = 128 rows x 256 cols (full N).
// W in LDS (128 KB pre-swizzled). A-fragments loaded NONTEMPORAL (x is
// read-once; keep it out of L3 so `support` stays L3-resident for the SpMM).
// Pack path: fminf/fmaxf (fuses to med3) + v_cvt_pk_bf16_f32.
// ---------------------------------------------------------------------------
__global__ __launch_bounds__(512) void gemm_mfma(
    const float* __restrict__ x, const unsigned short* __restrict__ wt,
    unsigned short* __restrict__ support) {
    __shared__ uint4 wlds[8192];    // 128 KB

    const int t    = threadIdx.x;
    const int lane = t & 63;
    const int w    = t >> 6;        // 0..7
    const int wr   = w >> 2;        // 0..1
    const int wc   = w & 3;         // 0..3
    const int l15  = lane & 15;
    const int l4   = lane >> 4;     // 0..3
    const int blockRow = blockIdx.x * 128;

    // ---- W -> LDS (linear copy; swizzle pre-applied) ----
    {
        const uint4* g = (const uint4*)wt;
        #pragma unroll
        for (int i = 0; i < 16; ++i)
            wlds[i * 512 + t] = g[i * 512 + t];
    }

    // A row pointers for this wave's 4 m-fragments (clamped for tail block)
    const float* aptr[4];
    #pragma unroll
    for (int m = 0; m < 4; ++m) {
        int r = blockRow + wr * 64 + m * 16 + l15;
        aptr[m] = x + (size_t)(r < N_NODES ? r : N_NODES - 1) * IN_F + l4 * 8;
    }

    f32x4 acc[4][4];
    #pragma unroll
    for (int m = 0; m < 4; ++m)
        #pragma unroll
        for (int n = 0; n < 4; ++n)
            acc[m][n] = (f32x4)0.f;

    __syncthreads();    // W ready

    #pragma unroll
    for (int s = 0; s < 8; ++s) {
        bf16x8 a[4], b[4];
        #pragma unroll
        for (int m = 0; m < 4; ++m) {
            f32x4 u0 = __builtin_nontemporal_load((const f32x4*)(aptr[m] + s * 32));
            f32x4 u1 = __builtin_nontemporal_load((const f32x4*)(aptr[m] + s * 32 + 4));
            union { unsigned u[4]; bf16x8 v; } pk;
            pk.u[0] = cvt_pk_bf16(clampf(u0[0]), clampf(u0[1]));
            pk.u[1] = cvt_pk_bf16(clampf(u0[2]), clampf(u0[3]));
            pk.u[2] = cvt_pk_bf16(clampf(u1[0]), clampf(u1[1]));
            pk.u[3] = cvt_pk_bf16(clampf(u1[2]), clampf(u1[3]));
            a[m] = pk.v;
        }
        #pragma unroll
        for (int n = 0; n < 4; ++n) {
            int ncol  = wc * 64 + n * 16 + l15;
            int chunk = ncol * 32 + ((s * 4 + l4) ^ (ncol & 7));
            b[n] = *(const bf16x8*)&wlds[chunk];
        }
        #pragma unroll
        for (int m = 0; m < 4; ++m)
            #pragma unroll
            for (int n = 0; n < 4; ++n)
                acc[m][n] = __builtin_amdgcn_mfma_f32_16x16x32_bf16(
                    a[m], b[n], acc[m][n], 0, 0, 0);
    }

    // ---- epilogue: acc -> LDS (bf16, chunk-swizzled) -> coalesced stores ----
    __syncthreads();    // all waves done reading W; safe to reuse wlds
    {
        char* sl = (char*)wlds;     // 128 rows x 512 B (64 KB)
        #pragma unroll
        for (int m = 0; m < 4; ++m) {
            #pragma unroll
            for (int n = 0; n < 4; ++n) {
                int col2 = (wc * 64 + n * 16 + l15) * 2;
                #pragma unroll
                for (int r = 0; r < 4; ++r) {
                    int row = wr * 64 + m * 16 + l4 * 4 + r;
                    int off = row * 512 + (col2 ^ (((row >> 2) & 3) << 4));
                    *(unsigned short*)(sl + off) = (unsigned short)f2bf(clampf(acc[m][n][r]));
                }
            }
        }
    }
    __syncthreads();
    {
        const uint4* sl4 = (const uint4*)wlds;
        #pragma unroll
        for (int i = 0; i < 8; ++i) {
            int c    = i * 512 + t;         // 0..4095 logical 16B chunks
            int row  = c >> 5;              // 0..127
            int q    = c & 31;              // chunk within row
            int grow = blockRow + row;
            if (grow < N_NODES) {
                uint4 v = sl4[row * 32 + (q ^ ((row >> 2) & 3))];
                *(uint4*)(support + (size_t)grow * OUT_F + q * 8) = v;
            }
        }
    }
}

// ---------------------------------------------------------------------------
// Kernel 3: out[r] = clip(relu(clip(sum val*support[c]) + bias)).
// One wave per row; lanes 0-31 even edge, 32-63 odd edge; 16B bf16x8 per
// lane. R2 loop shape (2 gathers in flight). cols/vals cached (L3-resident
// across replays); out store nontemporal (write-once, protect L3).
// ---------------------------------------------------------------------------
#define FMA8(g, v)                                                   \
    acc[0] += (v) * bflo((g).x); acc[1] += (v) * bfhi((g).x);        \
    acc[2] += (v) * bflo((g).y); acc[3] += (v) * bfhi((g).y);        \
    acc[4] += (v) * bflo((g).z); acc[5] += (v) * bfhi((g).z);        \
    acc[6] += (v) * bflo((g).w); acc[7] += (v) * bfhi((g).w);

__global__ __launch_bounds__(256) void spmm_out(
    const unsigned short* __restrict__ support, const int* __restrict__ row_ptr,
    const int* __restrict__ cols, const float* __restrict__ vals,
    const float* __restrict__ bias, float* __restrict__ out) {
    const int wid  = threadIdx.x >> 6;
    const int lane = threadIdx.x & 63;
    const int row  = blockIdx.x * 4 + wid;
    if (row >= N_NODES) return;

    const int e0   = row_ptr[row];
    const int e1   = row_ptr[row + 1];
    const int half = lane >> 5;
    const int c32  = lane & 31;

    const uint4* sup4 = (const uint4*)support;
    float acc[8] = {0.f,0.f,0.f,0.f,0.f,0.f,0.f,0.f};

    int e = e0;
    for (; e + 4 <= e1; e += 4) {
        int   ea = e + half, eb = ea + 2;
        int   ca = cols[ea], cb = cols[eb];
        float va = vals[ea], vb = vals[eb];
        uint4 ga = sup4[(size_t)ca * 32 + c32];
        uint4 gb = sup4[(size_t)cb * 32 + c32];
        FMA8(ga, va); FMA8(gb, vb);
    }
    for (; e < e1; e += 2) {
        int   ea = e + half;
        bool  ok = ea < e1;
        int   ca = cols[ok ? ea : e];
        float va = ok ? vals[ea] : 0.f;
        uint4 ga = sup4[(size_t)ca * 32 + c32];
        FMA8(ga, va);
    }

    #pragma unroll
    for (int j = 0; j < 8; ++j)
        acc[j] += __shfl_xor(acc[j], 32);

    const float4 b4 = ((const float4*)bias)[c32 * 2 + half];
    f32x4 o;
    o.x = fminf(fmaxf(clampf(acc[half * 4 + 0]) + b4.x, 0.f), CLAMP_V);
    o.y = fminf(fmaxf(clampf(acc[half * 4 + 1]) + b4.y, 0.f), CLAMP_V);
    o.z = fminf(fmaxf(clampf(acc[half * 4 + 2]) + b4.z, 0.f), CLAMP_V);
    o.w = fminf(fmaxf(clampf(acc[half * 4 + 3]) + b4.w, 0.f), CLAMP_V);
    __builtin_nontemporal_store(o, (f32x4*)(out + (size_t)row * OUT_F + c32 * 8 + half * 4));
}

// ---------------------------------------------------------------------------
extern "C" void kernel_launch(void* const* d_in, const int* in_sizes, int n_in,
                              void* d_out, int out_size, void* d_ws, size_t ws_size,
                              hipStream_t stream) {
    const float* x        = (const float*)d_in[0];
    const int*   adj_rows = (const int*)d_in[1];
    const int*   adj_cols = (const int*)d_in[2];
    const float* adj_vals = (const float*)d_in[3];
    const float* weight   = (const float*)d_in[4];
    const float* bias     = (const float*)d_in[5];
    float*       out      = (float*)d_out;

    // workspace: support bf16 [100000][256] | row_ptr [N+1] | wt (bf16 swizzled)
    char* ws = (char*)d_ws;
    unsigned short* support = (unsigned short*)ws;                   // 51,200,000 B
    int*            row_ptr = (int*)(ws + 51200000);                 //    400,004 B
    unsigned short* wt      = (unsigned short*)(ws + 51600064);      //    131,072 B

    convert_w<<<256, 256, 0, stream>>>(weight, wt);
    build_row_ptr<<<(N_NODES + 1 + 255) / 256, 256, 0, stream>>>(adj_rows, row_ptr);
    gemm_mfma<<<(N_NODES + 127) / 128, 512, 0, stream>>>(x, wt, support);
    spmm_out<<<(N_NODES + 3) / 4, 256, 0, stream>>>(support, row_ptr, adj_cols,
                                                    adj_vals, bias, out);
}